// Round 17
// baseline (109.681 us; speedup 1.0000x reference)
//
#include <hip/hip_runtime.h>
#include <hip/hip_bf16.h>
#include <math.h>

#define BB 8
#define C1D 384
#define C2D 192
#define LDIM 4096
#define ADIM 384
#define NH 8
#define DHD 48
#define KVLC 16
#define KVP_STRIDE 2352   // 48*48 partials + 48 expsums
#define LN_EPS 1e-5f

typedef short s8v __attribute__((ext_vector_type(8)));
typedef float f4v __attribute__((ext_vector_type(4)));

__device__ __forceinline__ unsigned short f2bf(float f) {
    unsigned u = __builtin_bit_cast(unsigned, f);
    unsigned r = (u + 0x7FFFu + ((u >> 16) & 1u)) >> 16;
    return (unsigned short)r;
}
__device__ __forceinline__ float bf2f(unsigned short h) {
    unsigned u = ((unsigned)h) << 16;
    return __builtin_bit_cast(float, u);
}
__device__ __forceinline__ void gload16(const void* g, void* l) {
    __builtin_amdgcn_global_load_lds((const __attribute__((address_space(1))) void*)g,
                                     (__attribute__((address_space(3))) void*)l, 16, 0, 0);
}

// ---------- shared transpose-cvt body; rmode: 0 = plain, 1 = K head-remap, 2 = V head-remap ----------
__device__ __forceinline__ void tcvt_body(const float* __restrict__ ib,
                                          unsigned short* __restrict__ ob,
                                          int R, int Cols, int c0, int r0,
                                          float* smem, int t, int rmode)
{
#pragma unroll
    for (int i = 0; i < 4; ++i) {
        int idx = t + i * 256;
        int rr = idx >> 5, cc = idx & 31;
        smem[rr * 33 + cc] = ib[(size_t)(r0 + rr) * Cols + c0 + cc];
    }
    __syncthreads();
#pragma unroll
    for (int i = 0; i < 2; ++i) {
        int idx = t + i * 256;
        int cc = idx >> 4, rp = (idx & 15) * 2;
        unsigned val = (unsigned)f2bf(smem[rp * 33 + cc]) | ((unsigned)f2bf(smem[(rp + 1) * 33 + cc]) << 16);
        int a = c0 + cc;
        int orow = (rmode == 0) ? a : ((a / 48) * 96 + (a % 48) + ((rmode == 2) ? 48 : 0));
        *(unsigned*)&ob[(size_t)orow * R + r0 + rp] = val;
    }
}

// ---------- all input/weight packs in ONE kernel ----------
// grid: [0,12288) x1 ; [12288,18432) x2 ; [18432,18720) weights
__global__ __launch_bounds__(256) void pack_all(
    const float* __restrict__ x1, const float* __restrict__ x2,
    const float* __restrict__ Wk, const float* __restrict__ Wv, const float* __restrict__ Wo,
    unsigned short* __restrict__ X1p, unsigned short* __restrict__ X2p,
    unsigned short* __restrict__ Wkvp, unsigned short* __restrict__ WoTp)
{
    __shared__ float smem[32 * 33];
    int bid = blockIdx.x;
    int t = threadIdx.x;
    if (bid < 12288) {
        int i = bid;
        int c0 = (i % 128) * 32, r0 = ((i / 128) % 12) * 32, b = i / 1536;
        tcvt_body(x1 + (size_t)b * C1D * LDIM, X1p + (size_t)b * C1D * LDIM,
                  C1D, LDIM, c0, r0, smem, t, 0);
    } else if (bid < 18432) {
        int i = bid - 12288;
        int c0 = (i % 128) * 32, r0 = ((i / 128) % 6) * 32, b = i / 768;
        tcvt_body(x2 + (size_t)b * C2D * LDIM, X2p + (size_t)b * C2D * LDIM,
                  C2D, LDIM, c0, r0, smem, t, 0);
    } else {
        int i = bid - 18432;
        if (i < 72)       tcvt_body(Wk, Wkvp, C2D,  ADIM, (i % 12) * 32, (i / 12) * 32, smem, t, 1);
        else if (i < 144) { i -= 72;  tcvt_body(Wv, Wkvp, C2D, ADIM, (i % 12) * 32, (i / 12) * 32, smem, t, 2); }
        else              { i -= 144; tcvt_body(Wo, WoTp, ADIM, C1D,  (i % 12) * 32, (i / 12) * 32, smem, t, 0); }
    }
}

// ---------- bf16 MFMA GEMM (used for W_res build), 1-D grid ----------
template<int KD, int BMODE>
__global__ __launch_bounds__(256) void gemm_mfma(
    const unsigned short* __restrict__ A, size_t Abs,
    const unsigned short* __restrict__ Bt, size_t Bbs,
    unsigned short* __restrict__ Out, size_t Obs, int Ncols, int gx, int gy)
{
    __shared__ unsigned short As[128 * 64];
    __shared__ unsigned short Bs[128 * 64];
    const int t = threadIdx.x;
    const int lane = t & 63;
    const int w = t >> 6;
    const int wm = w >> 1, wn = w & 1;
    const int nwg = gridDim.x;
    const int bid = blockIdx.x;
    const int swz = (bid & 7) * (nwg >> 3) + (bid >> 3);
    const int m0 = (swz % gx) * 128;
    const int n0 = ((swz / gx) % gy) * 128;
    const int b  = swz / (gx * gy);

    const unsigned short* Ab = A + Abs * b + (size_t)m0 * KD;
    const unsigned short* Bb = Bt + Bbs * b + (size_t)n0 * KD;

    f4v acc[4][4];
#pragma unroll
    for (int i = 0; i < 4; ++i)
#pragma unroll
        for (int j = 0; j < 4; ++j) acc[i][j] = (f4v)0.f;

    const int r_l = lane >> 3;
    const int q = lane & 7;

    for (int ks = 0; ks < KD; ks += 64) {
#pragma unroll
        for (int c = 0; c < 4; ++c) {
            int row = w * 32 + c * 8 + r_l;
            int koff = ((q ^ (row & 7)) << 3);
            gload16(Ab + (size_t)row * KD + ks + koff, &As[(w * 32 + c * 8) * 64]);
            gload16(Bb + (size_t)row * KD + ks + koff, &Bs[(w * 32 + c * 8) * 64]);
        }
        __syncthreads();
#pragma unroll
        for (int kh = 0; kh < 2; ++kh) {
            s8v af[4], bfr[4];
            int kq = kh * 4 + (lane >> 4);
#pragma unroll
            for (int m = 0; m < 4; ++m) {
                int row = wm * 64 + m * 16 + (lane & 15);
                af[m] = *(const s8v*)&As[row * 64 + ((kq ^ (row & 7)) << 3)];
            }
#pragma unroll
            for (int n = 0; n < 4; ++n) {
                int row = wn * 64 + n * 16 + (lane & 15);
                bfr[n] = *(const s8v*)&Bs[row * 64 + ((kq ^ (row & 7)) << 3)];
            }
#pragma unroll
            for (int m = 0; m < 4; ++m)
#pragma unroll
                for (int n = 0; n < 4; ++n)
                    acc[m][n] = __builtin_amdgcn_mfma_f32_16x16x32_bf16(af[m], bfr[n], acc[m][n], 0, 0, 0);
        }
        __syncthreads();
    }

#pragma unroll
    for (int m = 0; m < 4; ++m)
#pragma unroll
        for (int n = 0; n < 4; ++n) {
            int col = n0 + wn * 64 + n * 16 + (lane & 15);
#pragma unroll
            for (int r = 0; r < 4; ++r) {
                int row = m0 + wm * 64 + m * 16 + (lane >> 4) * 4 + r;
                float v = acc[m][n][r];
                if (BMODE == 3 && row == col) v += 1.f;
                Out[Obs * b + (size_t)row * Ncols + col] = f2bf(v);
            }
        }
}

// ---------- fused K/V projection + exp + kv outer-product partials ----------
__global__ __launch_bounds__(512) void kv_fused(
    const unsigned short* __restrict__ Wkvp,  // [8h][96][192] head-interleaved
    const unsigned short* __restrict__ X2p,   // [b][4096][192]
    const float* __restrict__ bk, const float* __restrict__ bv,
    float* __restrict__ kvpart, float inv_scale)
{
    __shared__ __align__(16) char lds[50176];
    unsigned short* As = (unsigned short*)lds;            // [96][64]  12KB (K-loop)
    unsigned short* Bs = (unsigned short*)(lds + 12288);  // [256][64] 32KB (K-loop)
    unsigned short* Ks = (unsigned short*)lds;            // [48][256] swz 24KB (alias, post-loop)
    unsigned short* Vs = (unsigned short*)(lds + 24576);  // [48][256] swz 24KB
    float* exps = (float*)(lds + 49152);                  // [48][4]

    const int t = threadIdx.x, lane = t & 63, w = t >> 6;
    const int wm = w >> 2, wn = w & 3;
    const int r_l = lane >> 3, q = lane & 7, qq = lane >> 4;
    const int bid = blockIdx.x;
    const int swz = (bid & 7) * 128 + (bid >> 3);
    const int lc = swz & 15, h = (swz >> 4) & 7, b = swz >> 7;

    const unsigned short* Ab = Wkvp + (size_t)h * 96 * C2D;
    const unsigned short* Bb = X2p + ((size_t)b * LDIM + lc * 256) * C2D;

    f4v acc[3][4];
#pragma unroll
    for (int m = 0; m < 3; ++m)
#pragma unroll
        for (int n = 0; n < 4; ++n) acc[m][n] = (f4v)0.f;

    for (int ks = 0; ks < C2D; ks += 64) {
#pragma unroll
        for (int c = 0; c < 2; ++c) {
            int blk = w + c * 8;
            if (blk < 12) {
                int row = blk * 8 + r_l;
                gload16(Ab + (size_t)row * C2D + ks + ((q ^ r_l) << 3), &As[blk * 8 * 64]);
            }
        }
#pragma unroll
        for (int c = 0; c < 4; ++c) {
            int blk = w * 4 + c;
            int row = blk * 8 + r_l;
            gload16(Bb + (size_t)row * C2D + ks + ((q ^ r_l) << 3), &Bs[blk * 8 * 64]);
        }
        __syncthreads();
#pragma unroll
        for (int kh = 0; kh < 2; ++kh) {
            int kq = kh * 4 + qq;
            s8v af[3], bfr[4];
#pragma unroll
            for (int m = 0; m < 3; ++m) {
                int row = wm * 48 + m * 16 + (lane & 15);
                af[m] = *(const s8v*)&As[row * 64 + ((kq ^ (row & 7)) << 3)];
            }
#pragma unroll
            for (int n = 0; n < 4; ++n) {
                int row = wn * 64 + n * 16 + (lane & 15);
                bfr[n] = *(const s8v*)&Bs[row * 64 + ((kq ^ (row & 7)) << 3)];
            }
#pragma unroll
            for (int m = 0; m < 3; ++m)
#pragma unroll
                for (int n = 0; n < 4; ++n)
                    acc[m][n] = __builtin_amdgcn_mfma_f32_16x16x32_bf16(af[m], bfr[n], acc[m][n], 0, 0, 0);
        }
        __syncthreads();
    }

    float es[3][4];
#pragma unroll
    for (int m = 0; m < 3; ++m)
#pragma unroll
        for (int r = 0; r < 4; ++r) es[m][r] = 0.f;

#pragma unroll
    for (int m = 0; m < 3; ++m)
#pragma unroll
        for (int r = 0; r < 4; ++r) {
            int rr = m * 16 + qq * 4 + r;
            float bias = (wm == 0) ? bk[h * DHD + rr] : bv[h * DHD + rr];
#pragma unroll
            for (int n = 0; n < 4; ++n) {
                int col = wn * 64 + n * 16 + (lane & 15);
                float v = acc[m][n][r] + bias;
                if (wm == 0) {
                    float e = __expf(v * inv_scale);
                    es[m][r] += e;
                    *(unsigned short*)((char*)Ks + rr * 512 + ((col * 2) ^ ((rr & 7) << 4))) = f2bf(e);
                } else {
                    *(unsigned short*)((char*)Vs + rr * 512 + ((col * 2) ^ ((rr & 7) << 4))) = f2bf(v);
                }
            }
        }
    if (wm == 0) {
#pragma unroll
        for (int m = 0; m < 3; ++m)
#pragma unroll
            for (int r = 0; r < 4; ++r) {
                float s = es[m][r];
                s += __shfl_xor(s, 1, 64);
                s += __shfl_xor(s, 2, 64);
                s += __shfl_xor(s, 4, 64);
                s += __shfl_xor(s, 8, 64);
                if ((lane & 15) == 0) exps[(m * 16 + qq * 4 + r) * 4 + wn] = s;
            }
    }
    __syncthreads();

    float* pp = kvpart + ((size_t)(b * NH + h) * KVLC + lc) * KVP_STRIDE;
    if (t < 48) pp[2304 + t] = exps[t * 4 + 0] + exps[t * 4 + 1] + exps[t * 4 + 2] + exps[t * 4 + 3];

    for (int fi = w; fi < 9; fi += 8) {
        int me = fi / 3, nd = fi % 3;
        f4v a2 = (f4v)0.f;
#pragma unroll
        for (int kc = 0; kc < 8; ++kc) {
            int k0 = kc * 32 + qq * 8;
            int e = me * 16 + (lane & 15);
            int d = nd * 16 + (lane & 15);
            s8v av = *(const s8v*)((char*)Vs + e * 512 + ((k0 * 2) ^ ((e & 7) << 4)));
            s8v bk_ = *(const s8v*)((char*)Ks + d * 512 + ((k0 * 2) ^ ((d & 7) << 4)));
            a2 = __builtin_amdgcn_mfma_f32_16x16x32_bf16(av, bk_, a2, 0, 0, 0);
        }
#pragma unroll
        for (int r = 0; r < 4; ++r) {
            int e = me * 16 + qq * 4 + r;
            int d = nd * 16 + (lane & 15);
            pp[e * DHD + d] = a2[r];
        }
    }
}

// ---------- KVf[bh][d*48+e] = (sum_lc part[e][d]) / (sum_lc expsum[d]) ----------
__global__ __launch_bounds__(256) void kv_finalize(const float* __restrict__ kvpart,
                                                   float* __restrict__ KVf)
{
    __shared__ float isl_s[DHD];
    int bh = blockIdx.x, t = threadIdx.x;
    const float* pp = kvpart + (size_t)bh * KVLC * KVP_STRIDE;
    if (t < DHD) {
        float s = 0.f;
#pragma unroll
        for (int lc = 0; lc < KVLC; ++lc) s += pp[lc * KVP_STRIDE + 2304 + t];
        isl_s[t] = 1.f / s;
    }
    __syncthreads();
    for (int idx = t; idx < DHD * DHD; idx += 256) {
        int d = idx / DHD, e = idx % DHD;
        float s = 0.f;
#pragma unroll
        for (int lc = 0; lc < KVLC; ++lc) s += pp[lc * KVP_STRIDE + e * DHD + d];
        KVf[(size_t)bh * DHD * DHD + idx] = s * isl_s[d];
    }
}

// ---------- merged: M-kernel (blocks 0..383) + btot (blocks 384..479) ----------
__global__ __launch_bounds__(256) void mb_kernel(const float* __restrict__ Wq,
                                                 const float* __restrict__ bq,
                                                 const float* __restrict__ KVf,
                                                 const float* __restrict__ Wo,
                                                 const float* __restrict__ bo,
                                                 unsigned short* __restrict__ M,
                                                 float* __restrict__ btot, float inv_scale)
{
    __shared__ float smem[DHD * DHD];
    int blk = blockIdx.x, t = threadIdx.x;
    if (blk < 384) {
        int c0 = (blk % 6) * 64, h = (blk / 6) % 8, b = blk / 48;
        for (int idx = t; idx < DHD * DHD; idx += 256)
            smem[idx] = KVf[((size_t)(b * NH + h)) * DHD * DHD + idx];
        __syncthreads();
        int cl = t >> 2, qq = t & 3;
        int c = c0 + cl;
        float wq[DHD];
#pragma unroll
        for (int d = 0; d < DHD; ++d) wq[d] = Wq[(size_t)c * ADIM + h * DHD + d];
        float s[12];
#pragma unroll
        for (int j = 0; j < 12; ++j) s[j] = 0.f;
#pragma unroll
        for (int d = 0; d < DHD; ++d) {
            float w = wq[d];
#pragma unroll
            for (int j = 0; j < 12; ++j)
                s[j] += w * smem[d * DHD + qq * 12 + j];
        }
#pragma unroll
        for (int j = 0; j < 12; ++j)
            M[((size_t)b * C1D + c) * ADIM + h * DHD + qq * 12 + j] = f2bf(s[j] * inv_scale);
    } else {
        int k = blk - 384;
        int cp0 = (k % 12) * 32, b = k / 12;
        for (int idx = t; idx < ADIM; idx += 256) {
            int h = idx / DHD, e = idx % DHD;
            float s = 0.f;
#pragma unroll
            for (int d = 0; d < DHD; ++d)
                s += bq[h * DHD + d] * KVf[((size_t)(b * NH + h)) * DHD * DHD + d * DHD + e];
            smem[idx] = s * inv_scale;
        }
        __syncthreads();
        int cp = cp0 + (t >> 3), part = t & 7;
        float s = 0.f;
#pragma unroll
        for (int i = 0; i < 48; ++i) {
            int he = part * 48 + i;
            s += smem[he] * Wo[(size_t)he * C1D + cp];
        }
        s += __shfl_xor(s, 1, 64);
        s += __shfl_xor(s, 2, 64);
        s += __shfl_xor(s, 4, 64);
        if (part == 0) btot[b * C1D + cp] = s + bo[cp];
    }
}

// ---------- transposed-output fused GEMM+LN: Y[b][c'][l]; A read directly from L2 ----------
// 384x128 tile, grid 256; A = WresT (L2-resident per XCD), B = X1p staged in LDS
__global__ __launch_bounds__(512) void gemm_lnT(
    const unsigned short* __restrict__ Wr,    // WresT [b][384][384]
    const unsigned short* __restrict__ Bx,    // X1p [b][4096][384]
    const float* __restrict__ btot,
    const float* __restrict__ gamma,
    const float* __restrict__ beta,
    float* __restrict__ Y)                    // [b][384][4096]
{
    __shared__ __align__(16) char lds[16896];
    unsigned short* Bs = (unsigned short*)lds;   // [128][64] bf16 (16 KB, K-loop)
    float* stats = (float*)lds;                  // [8][128][2] alias (8 KB, post-loop)
    float* fin   = (float*)(lds + 8192);         // [128][2]

    const int t = threadIdx.x;
    const int lane = t & 63;
    const int w = t >> 6;
    const int bid = blockIdx.x;
    const int swz = (bid & 7) * 32 + (bid >> 3);
    const int l0 = (swz & 31) * 128;
    const int b  = swz >> 5;

    const unsigned short* Ab = Wr + (size_t)b * C1D * C1D;
    const unsigned short* Bb = Bx + ((size_t)b * LDIM + l0) * C1D;

    f4v acc[3][8];
#pragma unroll
    for (int m = 0; m < 3; ++m)
#pragma unroll
        for (int n = 0; n < 8; ++n) acc[m][n] = (f4v)0.f;

    const int r_l = lane >> 3;
    const int q = lane & 7;

    for (int ks = 0; ks < C1D; ks += 64) {
#pragma unroll
        for (int c = 0; c < 2; ++c) {
            int row = w * 16 + c * 8 + r_l;   // row & 7 == r_l
            gload16(Bb + (size_t)row * C1D + ks + ((q ^ r_l) << 3), &Bs[(w * 16 + c * 8) * 64]);
        }
        __syncthreads();
#pragma unroll
        for (int kh = 0; kh < 2; ++kh) {
            int kq = kh * 4 + (lane >> 4);
            s8v af[3], bfr[8];
#pragma unroll
            for (int m = 0; m < 3; ++m) {
                int row = w * 48 + m * 16 + (lane & 15);
                af[m] = *(const s8v*)&Ab[(size_t)row * C1D + ks + kq * 8];   // direct L2 read
            }
#pragma unroll
            for (int n = 0; n < 8; ++n) {
                int row = n * 16 + (lane & 15);
                bfr[n] = *(const s8v*)&Bs[row * 64 + ((kq ^ (row & 7)) << 3)];
            }
#pragma unroll
            for (int m = 0; m < 3; ++m)
#pragma unroll
                for (int n = 0; n < 8; ++n)
                    acc[m][n] = __builtin_amdgcn_mfma_f32_16x16x32_bf16(af[m], bfr[n], acc[m][n], 0, 0, 0);
        }
        __syncthreads();
    }

    const int qq = lane >> 4;
    float btv[3][4], gmv[3][4], btav[3][4];
#pragma unroll
    for (int m = 0; m < 3; ++m)
#pragma unroll
        for (int r = 0; r < 4; ++r) {
            int row = w * 48 + m * 16 + qq * 4 + r;
            btv[m][r]  = btot[b * C1D + row];
            gmv[m][r]  = gamma[row];
            btav[m][r] = beta[row];
        }

    float cs[8], cq2[8];
#pragma unroll
    for (int n = 0; n < 8; ++n) { cs[n] = 0.f; cq2[n] = 0.f; }
#pragma unroll
    for (int m = 0; m < 3; ++m)
#pragma unroll
        for (int n = 0; n < 8; ++n)
#pragma unroll
            for (int r = 0; r < 4; ++r) {
                float v = acc[m][n][r] + btv[m][r];
                cs[n] += v; cq2[n] += v * v;
            }
#pragma unroll
    for (int n = 0; n < 8; ++n) {
        cs[n]  += __shfl_xor(cs[n], 16, 64);
        cs[n]  += __shfl_xor(cs[n], 32, 64);
        cq2[n] += __shfl_xor(cq2[n], 16, 64);
        cq2[n] += __shfl_xor(cq2[n], 32, 64);
    }
    if (lane < 16) {
#pragma unroll
        for (int n = 0; n < 8; ++n) {
            int col = n * 16 + lane;
            stats[(w * 128 + col) * 2 + 0] = cs[n];
            stats[(w * 128 + col) * 2 + 1] = cq2[n];
        }
    }
    __syncthreads();
    if (t < 256) {
        int col = t >> 1, which = t & 1;
        float s = 0.f;
#pragma unroll
        for (int w8 = 0; w8 < 8; ++w8) s += stats[(w8 * 128 + col) * 2 + which];
        fin[col * 2 + which] = s;
    }
    __syncthreads();

    float mu[8], rs[8];
#pragma unroll
    for (int n = 0; n < 8; ++n) {
        int cl = n * 16 + (lane & 15);
        float s = fin[cl * 2 + 0], s2 = fin[cl * 2 + 1];
        float m_ = s * (1.0f / C1D);
        mu[n] = m_;
        rs[n] = rsqrtf(s2 * (1.0f / C1D) - m_ * m_ + LN_EPS);
    }

    float* Yb = Y + (size_t)b * C1D * LDIM + l0;
#pragma unroll
    for (int m = 0; m < 3; ++m)
#pragma unroll
        for (int n = 0; n < 8; ++n)
#pragma unroll
            for (int r = 0; r < 4; ++r) {
                int row = w * 48 + m * 16 + qq * 4 + r;
                int cl = n * 16 + (lane & 15);
                float v = (acc[m][n][r] + btv[m][r] - mu[n]) * rs[n] * gmv[m][r] + btav[m][r];
                Yb[(size_t)row * LDIM + cl] = v;
            }
}

extern "C" void kernel_launch(void* const* d_in, const int* in_sizes, int n_in,
                              void* d_out, int out_size, void* d_ws, size_t ws_size,
                              hipStream_t stream) {
    const float* x1    = (const float*)d_in[0];
    const float* x2    = (const float*)d_in[1];
    const float* Wq    = (const float*)d_in[2];
    const float* bq    = (const float*)d_in[3];
    const float* Wk    = (const float*)d_in[4];
    const float* bk    = (const float*)d_in[5];
    const float* Wv    = (const float*)d_in[6];
    const float* bv    = (const float*)d_in[7];
    const float* Wo    = (const float*)d_in[8];
    const float* bo    = (const float*)d_in[9];
    const float* gamma = (const float*)d_in[10];
    const float* beta  = (const float*)d_in[11];
    float* out = (float*)d_out;

    char* p = (char*)d_ws;
    const size_t NB  = (size_t)BB * LDIM * ADIM;
    unsigned short* X1p = (unsigned short*)p; p += NB * 2;   // bf16 x1^T [b][l][c]
    unsigned short* X2p = (unsigned short*)p; p += NB;       // bf16 x2^T [b][l][c2]
    unsigned short* Wkvp= (unsigned short*)p; p += (size_t)768 * C2D * 2;  // head-interleaved [8h][96][192]
    unsigned short* WoTp= (unsigned short*)p; p += (size_t)C1D * ADIM * 2;
    float* kvpart = (float*)p; p += (size_t)BB * NH * KVLC * KVP_STRIDE * 4;
    float* KVf    = (float*)p; p += (size_t)BB * NH * DHD * DHD * 4;
    unsigned short* Mbuf = (unsigned short*)p; p += (size_t)BB * C1D * ADIM * 2;
    unsigned short* WresT = (unsigned short*)p; p += (size_t)BB * C1D * C1D * 2;
    float* btot   = (float*)p; p += (size_t)BB * C1D * 4;

    float inv_scale = powf((float)DHD, -0.25f);

    pack_all<<<18720, 256, 0, stream>>>(x1, x2, Wk, Wv, Wo, X1p, X2p, Wkvp, WoTp);

    kv_fused<<<1024, 512, 0, stream>>>(Wkvp, X2p, bk, bv, kvpart, inv_scale);

    kv_finalize<<<BB * NH, 256, 0, stream>>>(kvpart, KVf);

    mb_kernel<<<480, 256, 0, stream>>>(Wq, bq, KVf, Wo, bo, Mbuf, btot, inv_scale);

    gemm_mfma<ADIM, 3><<<72, 256, 0, stream>>>(
        WoTp, 0, Mbuf, (size_t)C1D * ADIM, WresT, (size_t)C1D * C1D, C1D, 3, 3);

    // 384x128 tile; A (WresT) read directly from L2, B (X1p) staged in 16 KB LDS
    gemm_lnT<<<256, 512, 0, stream>>>(WresT, X1p, btot, gamma, beta, out);
}

// Round 18
// 105.580 us; speedup vs baseline: 1.0388x; 1.0388x over previous
//
#include <hip/hip_runtime.h>
#include <hip/hip_bf16.h>
#include <math.h>

#define BB 8
#define C1D 384
#define C2D 192
#define LDIM 4096
#define ADIM 384
#define NH 8
#define DHD 48
#define KVLC 16
#define KVP_STRIDE 2352   // 48*48 partials + 48 expsums
#define LN_EPS 1e-5f

typedef short s8v __attribute__((ext_vector_type(8)));
typedef float f4v __attribute__((ext_vector_type(4)));

__device__ __forceinline__ unsigned short f2bf(float f) {
    unsigned u = __builtin_bit_cast(unsigned, f);
    unsigned r = (u + 0x7FFFu + ((u >> 16) & 1u)) >> 16;
    return (unsigned short)r;
}
__device__ __forceinline__ float bf2f(unsigned short h) {
    unsigned u = ((unsigned)h) << 16;
    return __builtin_bit_cast(float, u);
}
__device__ __forceinline__ void gload16(const void* g, void* l) {
    __builtin_amdgcn_global_load_lds((const __attribute__((address_space(1))) void*)g,
                                     (__attribute__((address_space(3))) void*)l, 16, 0, 0);
}

// ---------- shared transpose-cvt body; rmode: 0 = plain, 1 = K head-remap, 2 = V head-remap ----------
__device__ __forceinline__ void tcvt_body(const float* __restrict__ ib,
                                          unsigned short* __restrict__ ob,
                                          int R, int Cols, int c0, int r0,
                                          float* smem, int t, int rmode)
{
#pragma unroll
    for (int i = 0; i < 4; ++i) {
        int idx = t + i * 256;
        int rr = idx >> 5, cc = idx & 31;
        smem[rr * 33 + cc] = ib[(size_t)(r0 + rr) * Cols + c0 + cc];
    }
    __syncthreads();
#pragma unroll
    for (int i = 0; i < 2; ++i) {
        int idx = t + i * 256;
        int cc = idx >> 4, rp = (idx & 15) * 2;
        unsigned val = (unsigned)f2bf(smem[rp * 33 + cc]) | ((unsigned)f2bf(smem[(rp + 1) * 33 + cc]) << 16);
        int a = c0 + cc;
        int orow = (rmode == 0) ? a : ((a / 48) * 96 + (a % 48) + ((rmode == 2) ? 48 : 0));
        *(unsigned*)&ob[(size_t)orow * R + r0 + rp] = val;
    }
}

// ---------- all input/weight packs in ONE kernel ----------
// grid: [0,12288) x1 ; [12288,18432) x2 ; [18432,18720) weights
__global__ __launch_bounds__(256) void pack_all(
    const float* __restrict__ x1, const float* __restrict__ x2,
    const float* __restrict__ Wk, const float* __restrict__ Wv, const float* __restrict__ Wo,
    unsigned short* __restrict__ X1p, unsigned short* __restrict__ X2p,
    unsigned short* __restrict__ Wkvp, unsigned short* __restrict__ WoTp)
{
    __shared__ float smem[32 * 33];
    int bid = blockIdx.x;
    int t = threadIdx.x;
    if (bid < 12288) {
        int i = bid;
        int c0 = (i % 128) * 32, r0 = ((i / 128) % 12) * 32, b = i / 1536;
        tcvt_body(x1 + (size_t)b * C1D * LDIM, X1p + (size_t)b * C1D * LDIM,
                  C1D, LDIM, c0, r0, smem, t, 0);
    } else if (bid < 18432) {
        int i = bid - 12288;
        int c0 = (i % 128) * 32, r0 = ((i / 128) % 6) * 32, b = i / 768;
        tcvt_body(x2 + (size_t)b * C2D * LDIM, X2p + (size_t)b * C2D * LDIM,
                  C2D, LDIM, c0, r0, smem, t, 0);
    } else {
        int i = bid - 18432;
        if (i < 72)       tcvt_body(Wk, Wkvp, C2D,  ADIM, (i % 12) * 32, (i / 12) * 32, smem, t, 1);
        else if (i < 144) { i -= 72;  tcvt_body(Wv, Wkvp, C2D, ADIM, (i % 12) * 32, (i / 12) * 32, smem, t, 2); }
        else              { i -= 144; tcvt_body(Wo, WoTp, ADIM, C1D,  (i % 12) * 32, (i / 12) * 32, smem, t, 0); }
    }
}

// ---------- bf16 MFMA GEMM (used for W_res build), 1-D grid ----------
template<int KD, int BMODE>
__global__ __launch_bounds__(256) void gemm_mfma(
    const unsigned short* __restrict__ A, size_t Abs,
    const unsigned short* __restrict__ Bt, size_t Bbs,
    unsigned short* __restrict__ Out, size_t Obs, int Ncols, int gx, int gy)
{
    __shared__ unsigned short As[128 * 64];
    __shared__ unsigned short Bs[128 * 64];
    const int t = threadIdx.x;
    const int lane = t & 63;
    const int w = t >> 6;
    const int wm = w >> 1, wn = w & 1;
    const int nwg = gridDim.x;
    const int bid = blockIdx.x;
    const int swz = (bid & 7) * (nwg >> 3) + (bid >> 3);
    const int m0 = (swz % gx) * 128;
    const int n0 = ((swz / gx) % gy) * 128;
    const int b  = swz / (gx * gy);

    const unsigned short* Ab = A + Abs * b + (size_t)m0 * KD;
    const unsigned short* Bb = Bt + Bbs * b + (size_t)n0 * KD;

    f4v acc[4][4];
#pragma unroll
    for (int i = 0; i < 4; ++i)
#pragma unroll
        for (int j = 0; j < 4; ++j) acc[i][j] = (f4v)0.f;

    const int r_l = lane >> 3;
    const int q = lane & 7;

    for (int ks = 0; ks < KD; ks += 64) {
#pragma unroll
        for (int c = 0; c < 4; ++c) {
            int row = w * 32 + c * 8 + r_l;
            int koff = ((q ^ (row & 7)) << 3);
            gload16(Ab + (size_t)row * KD + ks + koff, &As[(w * 32 + c * 8) * 64]);
            gload16(Bb + (size_t)row * KD + ks + koff, &Bs[(w * 32 + c * 8) * 64]);
        }
        __syncthreads();
#pragma unroll
        for (int kh = 0; kh < 2; ++kh) {
            s8v af[4], bfr[4];
            int kq = kh * 4 + (lane >> 4);
#pragma unroll
            for (int m = 0; m < 4; ++m) {
                int row = wm * 64 + m * 16 + (lane & 15);
                af[m] = *(const s8v*)&As[row * 64 + ((kq ^ (row & 7)) << 3)];
            }
#pragma unroll
            for (int n = 0; n < 4; ++n) {
                int row = wn * 64 + n * 16 + (lane & 15);
                bfr[n] = *(const s8v*)&Bs[row * 64 + ((kq ^ (row & 7)) << 3)];
            }
#pragma unroll
            for (int m = 0; m < 4; ++m)
#pragma unroll
                for (int n = 0; n < 4; ++n)
                    acc[m][n] = __builtin_amdgcn_mfma_f32_16x16x32_bf16(af[m], bfr[n], acc[m][n], 0, 0, 0);
        }
        __syncthreads();
    }

#pragma unroll
    for (int m = 0; m < 4; ++m)
#pragma unroll
        for (int n = 0; n < 4; ++n) {
            int col = n0 + wn * 64 + n * 16 + (lane & 15);
#pragma unroll
            for (int r = 0; r < 4; ++r) {
                int row = m0 + wm * 64 + m * 16 + (lane >> 4) * 4 + r;
                float v = acc[m][n][r];
                if (BMODE == 3 && row == col) v += 1.f;
                Out[Obs * b + (size_t)row * Ncols + col] = f2bf(v);
            }
        }
}

// ---------- fused K/V projection + exp + kv outer-product partials ----------
__global__ __launch_bounds__(512) void kv_fused(
    const unsigned short* __restrict__ Wkvp,  // [8h][96][192] head-interleaved
    const unsigned short* __restrict__ X2p,   // [b][4096][192]
    const float* __restrict__ bk, const float* __restrict__ bv,
    float* __restrict__ kvpart, float inv_scale)
{
    __shared__ __align__(16) char lds[50176];
    unsigned short* As = (unsigned short*)lds;            // [96][64]  12KB (K-loop)
    unsigned short* Bs = (unsigned short*)(lds + 12288);  // [256][64] 32KB (K-loop)
    unsigned short* Ks = (unsigned short*)lds;            // [48][256] swz 24KB (alias, post-loop)
    unsigned short* Vs = (unsigned short*)(lds + 24576);  // [48][256] swz 24KB
    float* exps = (float*)(lds + 49152);                  // [48][4]

    const int t = threadIdx.x, lane = t & 63, w = t >> 6;
    const int wm = w >> 2, wn = w & 3;
    const int r_l = lane >> 3, q = lane & 7, qq = lane >> 4;
    const int bid = blockIdx.x;
    const int swz = (bid & 7) * 128 + (bid >> 3);
    const int lc = swz & 15, h = (swz >> 4) & 7, b = swz >> 7;

    const unsigned short* Ab = Wkvp + (size_t)h * 96 * C2D;
    const unsigned short* Bb = X2p + ((size_t)b * LDIM + lc * 256) * C2D;

    f4v acc[3][4];
#pragma unroll
    for (int m = 0; m < 3; ++m)
#pragma unroll
        for (int n = 0; n < 4; ++n) acc[m][n] = (f4v)0.f;

    for (int ks = 0; ks < C2D; ks += 64) {
#pragma unroll
        for (int c = 0; c < 2; ++c) {
            int blk = w + c * 8;
            if (blk < 12) {
                int row = blk * 8 + r_l;
                gload16(Ab + (size_t)row * C2D + ks + ((q ^ r_l) << 3), &As[blk * 8 * 64]);
            }
        }
#pragma unroll
        for (int c = 0; c < 4; ++c) {
            int blk = w * 4 + c;
            int row = blk * 8 + r_l;
            gload16(Bb + (size_t)row * C2D + ks + ((q ^ r_l) << 3), &Bs[blk * 8 * 64]);
        }
        __syncthreads();
#pragma unroll
        for (int kh = 0; kh < 2; ++kh) {
            int kq = kh * 4 + qq;
            s8v af[3], bfr[4];
#pragma unroll
            for (int m = 0; m < 3; ++m) {
                int row = wm * 48 + m * 16 + (lane & 15);
                af[m] = *(const s8v*)&As[row * 64 + ((kq ^ (row & 7)) << 3)];
            }
#pragma unroll
            for (int n = 0; n < 4; ++n) {
                int row = wn * 64 + n * 16 + (lane & 15);
                bfr[n] = *(const s8v*)&Bs[row * 64 + ((kq ^ (row & 7)) << 3)];
            }
#pragma unroll
            for (int m = 0; m < 3; ++m)
#pragma unroll
                for (int n = 0; n < 4; ++n)
                    acc[m][n] = __builtin_amdgcn_mfma_f32_16x16x32_bf16(af[m], bfr[n], acc[m][n], 0, 0, 0);
        }
        __syncthreads();
    }

    float es[3][4];
#pragma unroll
    for (int m = 0; m < 3; ++m)
#pragma unroll
        for (int r = 0; r < 4; ++r) es[m][r] = 0.f;

#pragma unroll
    for (int m = 0; m < 3; ++m)
#pragma unroll
        for (int r = 0; r < 4; ++r) {
            int rr = m * 16 + qq * 4 + r;
            float bias = (wm == 0) ? bk[h * DHD + rr] : bv[h * DHD + rr];
#pragma unroll
            for (int n = 0; n < 4; ++n) {
                int col = wn * 64 + n * 16 + (lane & 15);
                float v = acc[m][n][r] + bias;
                if (wm == 0) {
                    float e = __expf(v * inv_scale);
                    es[m][r] += e;
                    *(unsigned short*)((char*)Ks + rr * 512 + ((col * 2) ^ ((rr & 7) << 4))) = f2bf(e);
                } else {
                    *(unsigned short*)((char*)Vs + rr * 512 + ((col * 2) ^ ((rr & 7) << 4))) = f2bf(v);
                }
            }
        }
    if (wm == 0) {
#pragma unroll
        for (int m = 0; m < 3; ++m)
#pragma unroll
            for (int r = 0; r < 4; ++r) {
                float s = es[m][r];
                s += __shfl_xor(s, 1, 64);
                s += __shfl_xor(s, 2, 64);
                s += __shfl_xor(s, 4, 64);
                s += __shfl_xor(s, 8, 64);
                if ((lane & 15) == 0) exps[(m * 16 + qq * 4 + r) * 4 + wn] = s;
            }
    }
    __syncthreads();

    float* pp = kvpart + ((size_t)(b * NH + h) * KVLC + lc) * KVP_STRIDE;
    if (t < 48) pp[2304 + t] = exps[t * 4 + 0] + exps[t * 4 + 1] + exps[t * 4 + 2] + exps[t * 4 + 3];

    for (int fi = w; fi < 9; fi += 8) {
        int me = fi / 3, nd = fi % 3;
        f4v a2 = (f4v)0.f;
#pragma unroll
        for (int kc = 0; kc < 8; ++kc) {
            int k0 = kc * 32 + qq * 8;
            int e = me * 16 + (lane & 15);
            int d = nd * 16 + (lane & 15);
            s8v av = *(const s8v*)((char*)Vs + e * 512 + ((k0 * 2) ^ ((e & 7) << 4)));
            s8v bk_ = *(const s8v*)((char*)Ks + d * 512 + ((k0 * 2) ^ ((d & 7) << 4)));
            a2 = __builtin_amdgcn_mfma_f32_16x16x32_bf16(av, bk_, a2, 0, 0, 0);
        }
#pragma unroll
        for (int r = 0; r < 4; ++r) {
            int e = me * 16 + qq * 4 + r;
            int d = nd * 16 + (lane & 15);
            pp[e * DHD + d] = a2[r];
        }
    }
}

// ---------- KVf[bh][d*48+e] = (sum_lc part[e][d]) / (sum_lc expsum[d]) ----------
__global__ __launch_bounds__(256) void kv_finalize(const float* __restrict__ kvpart,
                                                   float* __restrict__ KVf)
{
    __shared__ float isl_s[DHD];
    int bh = blockIdx.x, t = threadIdx.x;
    const float* pp = kvpart + (size_t)bh * KVLC * KVP_STRIDE;
    if (t < DHD) {
        float s = 0.f;
#pragma unroll
        for (int lc = 0; lc < KVLC; ++lc) s += pp[lc * KVP_STRIDE + 2304 + t];
        isl_s[t] = 1.f / s;
    }
    __syncthreads();
    for (int idx = t; idx < DHD * DHD; idx += 256) {
        int d = idx / DHD, e = idx % DHD;
        float s = 0.f;
#pragma unroll
        for (int lc = 0; lc < KVLC; ++lc) s += pp[lc * KVP_STRIDE + e * DHD + d];
        KVf[(size_t)bh * DHD * DHD + idx] = s * isl_s[d];
    }
}

// ---------- merged: M-kernel (blocks 0..383) + btot (blocks 384..479) ----------
__global__ __launch_bounds__(256) void mb_kernel(const float* __restrict__ Wq,
                                                 const float* __restrict__ bq,
                                                 const float* __restrict__ KVf,
                                                 const float* __restrict__ Wo,
                                                 const float* __restrict__ bo,
                                                 unsigned short* __restrict__ M,
                                                 float* __restrict__ btot, float inv_scale)
{
    __shared__ float smem[DHD * DHD];
    int blk = blockIdx.x, t = threadIdx.x;
    if (blk < 384) {
        int c0 = (blk % 6) * 64, h = (blk / 6) % 8, b = blk / 48;
        for (int idx = t; idx < DHD * DHD; idx += 256)
            smem[idx] = KVf[((size_t)(b * NH + h)) * DHD * DHD + idx];
        __syncthreads();
        int cl = t >> 2, qq = t & 3;
        int c = c0 + cl;
        float wq[DHD];
#pragma unroll
        for (int d = 0; d < DHD; ++d) wq[d] = Wq[(size_t)c * ADIM + h * DHD + d];
        float s[12];
#pragma unroll
        for (int j = 0; j < 12; ++j) s[j] = 0.f;
#pragma unroll
        for (int d = 0; d < DHD; ++d) {
            float w = wq[d];
#pragma unroll
            for (int j = 0; j < 12; ++j)
                s[j] += w * smem[d * DHD + qq * 12 + j];
        }
#pragma unroll
        for (int j = 0; j < 12; ++j)
            M[((size_t)b * C1D + c) * ADIM + h * DHD + qq * 12 + j] = f2bf(s[j] * inv_scale);
    } else {
        int k = blk - 384;
        int cp0 = (k % 12) * 32, b = k / 12;
        for (int idx = t; idx < ADIM; idx += 256) {
            int h = idx / DHD, e = idx % DHD;
            float s = 0.f;
#pragma unroll
            for (int d = 0; d < DHD; ++d)
                s += bq[h * DHD + d] * KVf[((size_t)(b * NH + h)) * DHD * DHD + d * DHD + e];
            smem[idx] = s * inv_scale;
        }
        __syncthreads();
        int cp = cp0 + (t >> 3), part = t & 7;
        float s = 0.f;
#pragma unroll
        for (int i = 0; i < 48; ++i) {
            int he = part * 48 + i;
            s += smem[he] * Wo[(size_t)he * C1D + cp];
        }
        s += __shfl_xor(s, 1, 64);
        s += __shfl_xor(s, 2, 64);
        s += __shfl_xor(s, 4, 64);
        if (part == 0) btot[b * C1D + cp] = s + bo[cp];
    }
}

// ---------- transposed-output fused GEMM+LN: Y[b][c'][l] directly (round-15 form) ----------
// A = WresT (rows c', M=384 full, LDS-staged), B = X1p (rows l, N=128/block); 8 waves x 48 rows
__global__ __launch_bounds__(512) void gemm_lnT(
    const unsigned short* __restrict__ Wr,    // WresT [b][384][384]
    const unsigned short* __restrict__ Bx,    // X1p [b][4096][384]
    const float* __restrict__ btot,
    const float* __restrict__ gamma,
    const float* __restrict__ beta,
    float* __restrict__ Y)                    // [b][384][4096]
{
    __shared__ __align__(16) char lds[65536];
    unsigned short* As = (unsigned short*)lds;                 // [384][64] bf16 (48 KB)
    unsigned short* Bs = (unsigned short*)(lds + 49152);       // [128][64] bf16 (16 KB)
    float* stats = (float*)lds;                                // [8][128][2] alias (8 KB)
    float* fin   = (float*)(lds + 8192);                       // [128][2]

    const int t = threadIdx.x;
    const int lane = t & 63;
    const int w = t >> 6;           // wave owns rows [w*48, w*48+48)
    const int bid = blockIdx.x;
    const int swz = (bid & 7) * 32 + (bid >> 3);
    const int l0 = (swz & 31) * 128;
    const int b  = swz >> 5;

    const unsigned short* Ab = Wr + (size_t)b * C1D * C1D;
    const unsigned short* Bb = Bx + ((size_t)b * LDIM + l0) * C1D;

    f4v acc[3][8];
#pragma unroll
    for (int m = 0; m < 3; ++m)
#pragma unroll
        for (int n = 0; n < 8; ++n) acc[m][n] = (f4v)0.f;

    const int r_l = lane >> 3;
    const int q = lane & 7;

    for (int ks = 0; ks < C1D; ks += 64) {
#pragma unroll
        for (int c = 0; c < 6; ++c) {
            int row = w * 48 + c * 8 + r_l;
            int koff = ((q ^ (row & 7)) << 3);
            gload16(Ab + (size_t)row * C1D + ks + koff, &As[(w * 48 + c * 8) * 64]);
        }
#pragma unroll
        for (int c = 0; c < 2; ++c) {
            int row = w * 16 + c * 8 + r_l;
            int koff = ((q ^ (row & 7)) << 3);
            gload16(Bb + (size_t)row * C1D + ks + koff, &Bs[(w * 16 + c * 8) * 64]);
        }
        __syncthreads();
#pragma unroll
        for (int kh = 0; kh < 2; ++kh) {
            int kq = kh * 4 + (lane >> 4);
            s8v af[3], bfr[8];
#pragma unroll
            for (int m = 0; m < 3; ++m) {
                int row = w * 48 + m * 16 + (lane & 15);
                af[m] = *(const s8v*)&As[row * 64 + ((kq ^ (row & 7)) << 3)];
            }
#pragma unroll
            for (int n = 0; n < 8; ++n) {
                int row = n * 16 + (lane & 15);
                bfr[n] = *(const s8v*)&Bs[row * 64 + ((kq ^ (row & 7)) << 3)];
            }
#pragma unroll
            for (int m = 0; m < 3; ++m)
#pragma unroll
                for (int n = 0; n < 8; ++n)
                    acc[m][n] = __builtin_amdgcn_mfma_f32_16x16x32_bf16(af[m], bfr[n], acc[m][n], 0, 0, 0);
        }
        __syncthreads();
    }

    const int qq = lane >> 4;
    float btv[3][4], gmv[3][4], btav[3][4];
#pragma unroll
    for (int m = 0; m < 3; ++m)
#pragma unroll
        for (int r = 0; r < 4; ++r) {
            int row = w * 48 + m * 16 + qq * 4 + r;
            btv[m][r]  = btot[b * C1D + row];
            gmv[m][r]  = gamma[row];
            btav[m][r] = beta[row];
        }

    float cs[8], cq2[8];
#pragma unroll
    for (int n = 0; n < 8; ++n) { cs[n] = 0.f; cq2[n] = 0.f; }
#pragma unroll
    for (int m = 0; m < 3; ++m)
#pragma unroll
        for (int n = 0; n < 8; ++n)
#pragma unroll
            for (int r = 0; r < 4; ++r) {
                float v = acc[m][n][r] + btv[m][r];
                cs[n] += v; cq2[n] += v * v;
            }
#pragma unroll
    for (int n = 0; n < 8; ++n) {
        cs[n]  += __shfl_xor(cs[n], 16, 64);
        cs[n]  += __shfl_xor(cs[n], 32, 64);
        cq2[n] += __shfl_xor(cq2[n], 16, 64);
        cq2[n] += __shfl_xor(cq2[n], 32, 64);
    }
    if (lane < 16) {
#pragma unroll
        for (int n = 0; n < 8; ++n) {
            int col = n * 16 + lane;
            stats[(w * 128 + col) * 2 + 0] = cs[n];
            stats[(w * 128 + col) * 2 + 1] = cq2[n];
        }
    }
    __syncthreads();
    if (t < 256) {
        int col = t >> 1, which = t & 1;
        float s = 0.f;
#pragma unroll
        for (int w8 = 0; w8 < 8; ++w8) s += stats[(w8 * 128 + col) * 2 + which];
        fin[col * 2 + which] = s;
    }
    __syncthreads();

    float mu[8], rs[8];
#pragma unroll
    for (int n = 0; n < 8; ++n) {
        int cl = n * 16 + (lane & 15);
        float s = fin[cl * 2 + 0], s2 = fin[cl * 2 + 1];
        float m_ = s * (1.0f / C1D);
        mu[n] = m_;
        rs[n] = rsqrtf(s2 * (1.0f / C1D) - m_ * m_ + LN_EPS);
    }

    float* Yb = Y + (size_t)b * C1D * LDIM + l0;
#pragma unroll
    for (int m = 0; m < 3; ++m)
#pragma unroll
        for (int n = 0; n < 8; ++n)
#pragma unroll
            for (int r = 0; r < 4; ++r) {
                int row = w * 48 + m * 16 + qq * 4 + r;
                int cl = n * 16 + (lane & 15);
                float v = (acc[m][n][r] + btv[m][r] - mu[n]) * rs[n] * gmv[m][r] + btav[m][r];
                Yb[(size_t)row * LDIM + cl] = v;
            }
}

extern "C" void kernel_launch(void* const* d_in, const int* in_sizes, int n_in,
                              void* d_out, int out_size, void* d_ws, size_t ws_size,
                              hipStream_t stream) {
    const float* x1    = (const float*)d_in[0];
    const float* x2    = (const float*)d_in[1];
    const float* Wq    = (const float*)d_in[2];
    const float* bq    = (const float*)d_in[3];
    const float* Wk    = (const float*)d_in[4];
    const float* bk    = (const float*)d_in[5];
    const float* Wv    = (const float*)d_in[6];
    const float* bv    = (const float*)d_in[7];
    const float* Wo    = (const float*)d_in[8];
    const float* bo    = (const float*)d_in[9];
    const float* gamma = (const float*)d_in[10];
    const float* beta  = (const float*)d_in[11];
    float* out = (float*)d_out;

    char* p = (char*)d_ws;
    const size_t NB  = (size_t)BB * LDIM * ADIM;
    unsigned short* X1p = (unsigned short*)p; p += NB * 2;   // bf16 x1^T [b][l][c]
    unsigned short* X2p = (unsigned short*)p; p += NB;       // bf16 x2^T [b][l][c2]
    unsigned short* Wkvp= (unsigned short*)p; p += (size_t)768 * C2D * 2;  // head-interleaved [8h][96][192]
    unsigned short* WoTp= (unsigned short*)p; p += (size_t)C1D * ADIM * 2;
    float* kvpart = (float*)p; p += (size_t)BB * NH * KVLC * KVP_STRIDE * 4;
    float* KVf    = (float*)p; p += (size_t)BB * NH * DHD * DHD * 4;
    unsigned short* Mbuf = (unsigned short*)p; p += (size_t)BB * C1D * ADIM * 2;
    unsigned short* WresT = (unsigned short*)p; p += (size_t)BB * C1D * C1D * 2;
    float* btot   = (float*)p; p += (size_t)BB * C1D * 4;

    float inv_scale = powf((float)DHD, -0.25f);

    pack_all<<<18720, 256, 0, stream>>>(x1, x2, Wk, Wv, Wo, X1p, X2p, Wkvp, WoTp);

    kv_fused<<<1024, 512, 0, stream>>>(Wkvp, X2p, bk, bv, kvpart, inv_scale);

    kv_finalize<<<BB * NH, 256, 0, stream>>>(kvpart, KVf);

    mb_kernel<<<480, 256, 0, stream>>>(Wq, bq, KVf, Wo, bo, Mbuf, btot, inv_scale);

    gemm_mfma<ADIM, 3><<<72, 256, 0, stream>>>(
        WoTp, 0, Mbuf, (size_t)C1D * ADIM, WresT, (size_t)C1D * C1D, C1D, 3, 3);

    gemm_lnT<<<256, 512, 0, stream>>>(WresT, X1p, btot, gamma, beta, out);
}